// Round 20
// baseline (282.814 us; speedup 1.0000x reference)
//
#include <hip/hip_runtime.h>
#include <math.h>

// Problem constants
#define R_ 5
#define NN 68        // N_NODES == LATENT
#define KK 32        // neighbors per node
#define NL 3         // GCN layers
#define LAT 68
#define NPAD 80              // padded node dim: 4 waves x 5 float4-cols
#define ROWQ (NN / 4)        // 17 float4 per node row
#define NF4 ((NN * NN) / 4)  // 1156 float4 per output row
#define BBK2 16              // batches per K2 block
#define LSTR 344             // LDS row stride (floats) for K2, 16B-aligned
#define NPREP (R_ * NL)      // 15 densify blocks inside prep_k
#define WPAD_FLOATS (R_ * 4 * NN * NPAD)  // 108800
#define BPAD_FLOATS (R_ * 4 * NPAD)      // 1600

// ---------------- P: merged prep (densify+pad, fc pack, z-transpose) -------
// blocks [0,15): densify gw -> wpad stages 1..3 (80-col padded rows)
// blocks [15,20): fc_w -> wpad stage 0; biases -> bpad (padded)
// blocks [20, 20+B/64): zT[l][b] transpose tiles
__global__ __launch_bounds__(256) void prep_k(
    const float* __restrict__ z, const int* __restrict__ adj,
    const float* __restrict__ fc_w, const float* __restrict__ fc_b,
    const float* __restrict__ gw, const float* __restrict__ gb,
    float* __restrict__ wpad, float* __restrict__ bpad,
    float* __restrict__ zT, int B) {
  const int t = threadIdx.x;
  if (blockIdx.x < NPREP) {
    const int rl = blockIdx.x;  // r*NL + l
    const int r = rl / NL, l = rl - r * NL;
    const int stage = 1 + l;
    __shared__ float col[NN][NN + 4];
    for (int i = t; i < NN * (NN + 4); i += 256) (&col[0][0])[i] = 0.0f;
    __syncthreads();
    if (t < NN) {
      const int n = t;  // thread owns column n -> no races
      const int* ar = adj + n * KK;
      const float* wr = gw + ((size_t)rl * NN + n) * KK;
      for (int k = 0; k < KK; ++k) col[ar[k]][n] += wr[k];
    }
    __syncthreads();
    float* wout = wpad + (size_t)((r * 4 + stage) * NN) * NPAD;
    for (int i = t; i < NN * NPAD; i += 256) {
      const int m = i / NPAD, n = i - m * NPAD;
      wout[i] = (n < NN) ? col[m][n] : 0.0f;
    }
  } else if (blockIdx.x < NPREP + R_) {
    const int r = blockIdx.x - NPREP;
    float* wout = wpad + (size_t)((r * 4 + 0) * NN) * NPAD;
    for (int i = t; i < NN * NPAD; i += 256) {
      const int m = i / NPAD, n = i - m * NPAD;
      wout[i] = (n < NN) ? fc_w[((size_t)r * NN + m) * NN + n] : 0.0f;
    }
    for (int i = t; i < 4 * NPAD; i += 256) {
      const int st = i / NPAD, n = i - st * NPAD;
      float v = 0.0f;
      if (n < NN)
        v = (st == 0) ? fc_b[r * NN + n]
                      : gb[((size_t)r * NL + st - 1) * NN + n];
      bpad[(r * 4 + st) * NPAD + n] = v;
    }
  } else {
    const int b0 = (blockIdx.x - (NPREP + R_)) * 64;
    __shared__ float zls[64][LAT + 1];  // +1: stride 69, conflict-free
    for (int idx = t; idx < 64 * ROWQ; idx += 256) {
      const int row = idx / ROWQ, q = idx - row * ROWQ;
      const float4 v =
          *reinterpret_cast<const float4*>(z + (size_t)(b0 + row) * LAT + 4 * q);
      zls[row][4 * q + 0] = v.x;
      zls[row][4 * q + 1] = v.y;
      zls[row][4 * q + 2] = v.z;
      zls[row][4 * q + 3] = v.w;
    }
    __syncthreads();
    for (int idx = t; idx < LAT * 64; idx += 256) {
      const int l = idx >> 6, bb = idx & 63;
      zT[(size_t)l * B + b0 + bb] = zls[bb][l];
    }
  }
}

// ---------------- K1: GEMM-chain — VMEM weight stream (in-order vmcnt) -----
// Wave w owns padded cols [20w, 20w+20) = 5 static float4 accumulators (no
// runtime guards — v5's killer). Weight rows read as 5 global_load_dwordx4
// with an opaque-VGPR zero defeating scalarization: VMEM vmcnt is IN-ORDER,
// so the compiler emits counted vmcnt(N) waits and pipelines rows deeply —
// unlike SMEM, where out-of-order completion forces full lgkmcnt(0) drains
// (R12's verified stall; its chunking removed 64/68 drains, this removes the
// per-row drains inside chunks). xm ds_reads use lgkmcnt: separate counter.
__global__ __launch_bounds__(256) void chain_k(
    const float* __restrict__ zT, const float* __restrict__ wpad,
    const float* __restrict__ bpad, float* __restrict__ X, int B, int nb) {
  const int t = threadIdx.x;
  const int lane = t & 63;
  const int w = __builtin_amdgcn_readfirstlane(t >> 6);  // wave id (scalar)
  const int c0 = 20 * w;  // first padded col owned
  const int r = blockIdx.x / nb;
  const int b0 = (blockIdx.x - r * nb) * 64;

  __shared__ float xs[NN][64];  // 17.4 KB; z, then x, per stage

  for (int idx = t; idx < NN * 64; idx += 256) {
    const int m = idx >> 6;
    xs[m][idx & 63] = zT[(size_t)m * B + b0 + (idx & 63)];
  }
  __syncthreads();

  int vzero;  // opaque 0 in a VGPR: compiler cannot prove uniform -> VMEM path
  asm("v_mov_b32 %0, 0" : "=v"(vzero));

  float4 acc[5];  // 20 padded nodes (statically indexed)

#pragma unroll 1
  for (int stage = 0; stage < 1 + NL; ++stage) {
    const float* wbS =
        wpad + (size_t)((r * 4 + stage) * NN) * NPAD + c0 + vzero;
    const float* bpS = bpad + (r * 4 + stage) * NPAD + c0 + vzero;
#pragma unroll
    for (int j = 0; j < 5; ++j)
      acc[j] = *reinterpret_cast<const float4*>(bpS + 4 * j);

#pragma unroll 4
    for (int m = 0; m < NN; ++m) {
      const float xm = xs[m][lane];        // stride-64, conflict-free
      const float* wr = wbS + m * NPAD;    // per-lane (uniform value) -> VMEM
#pragma unroll
      for (int j = 0; j < 5; ++j) {
        const float4 ww = *reinterpret_cast<const float4*>(wr + 4 * j);
        acc[j].x = fmaf(xm, ww.x, acc[j].x);
        acc[j].y = fmaf(xm, ww.y, acc[j].y);
        acc[j].z = fmaf(xm, ww.z, acc[j].z);
        acc[j].w = fmaf(xm, ww.w, acc[j].w);
      }
    }
    if (stage > 0) {  // sigmoid (pad lanes harmless, never stored)
#pragma unroll
      for (int j = 0; j < 5; ++j) {
        acc[j].x = 1.0f / (1.0f + __expf(-acc[j].x));
        acc[j].y = 1.0f / (1.0f + __expf(-acc[j].y));
        acc[j].z = 1.0f / (1.0f + __expf(-acc[j].z));
        acc[j].w = 1.0f / (1.0f + __expf(-acc[j].w));
      }
    }
    if (stage < NL) {
      __syncthreads();  // all reads of old xs done
      if (w < 3) {      // scalar branch; waves 0-2 store 20 nodes
#pragma unroll
        for (int j = 0; j < 5; ++j) {
          const int n0c = c0 + 4 * j;
          xs[n0c + 0][lane] = acc[j].x;
          xs[n0c + 1][lane] = acc[j].y;
          xs[n0c + 2][lane] = acc[j].z;
          xs[n0c + 3][lane] = acc[j].w;
        }
      } else {  // wave 3: nodes 60..67 only
#pragma unroll
        for (int j = 0; j < 2; ++j) {
          const int n0c = 60 + 4 * j;
          xs[n0c + 0][lane] = acc[j].x;
          xs[n0c + 1][lane] = acc[j].y;
          xs[n0c + 2][lane] = acc[j].z;
          xs[n0c + 3][lane] = acc[j].w;
        }
      }
      __syncthreads();
    }
  }

  // ---- final X -> ws, layout [r*68+n][b]: coalesced 256B rows ----
  float* Xb = X + ((size_t)r * NN + c0) * B + b0 + lane;
  if (w < 3) {
#pragma unroll
    for (int j = 0; j < 20; ++j)
      Xb[(size_t)j * B] = reinterpret_cast<const float*>(&acc[j >> 2])[j & 3];
  } else {
#pragma unroll
    for (int j = 0; j < 8; ++j)
      Xb[(size_t)j * B] = reinterpret_cast<const float*>(&acc[j >> 2])[j & 3];
  }
}

// ---------------- K2: outer product, flat store, 4-DEEP STORE PIPELINE -----
// (R16 verbatim — measured best: 4 KB in flight/wave; 8-deep neutral/worse)
__global__ __launch_bounds__(256) void outer_k(const float* __restrict__ X,
                                               float* __restrict__ out, int B) {
  const int t = threadIdx.x;
  const int b0 = blockIdx.x * BBK2;
  __shared__ float xls[BBK2 * LSTR];

  // stage X[rn][b0..b0+15] -> xls[bb][rn]; reads are exact 64B lines
  for (int idx = t; idx < R_ * NN * BBK2; idx += 256) {
    const int rn = idx >> 4, bb = idx & (BBK2 - 1);
    xls[bb * LSTR + rn] = X[(size_t)rn * B + b0 + bb];
  }
  __syncthreads();

  float4* ob = reinterpret_cast<float4*>(out) + (size_t)b0 * NF4;
  const int total = BBK2 * NF4;  // 18496 = 18*1024 + 64
#pragma unroll 1
  for (int base = t; base < total; base += 1024) {
    float4 av[4];  // 4 independent accumulator sets (statically indexed)
#pragma unroll
    for (int u = 0; u < 4; ++u) {
      const int fg = base + u * 256;
      if (fg < total) {
        const int bb = fg / NF4;
        const int f = fg - bb * NF4;
        const int i = f / ROWQ;
        const int q = f - i * ROWQ;
        const float* xb = &xls[bb * LSTR];
        float4 a = make_float4(0.f, 0.f, 0.f, 0.f);
#pragma unroll
        for (int r = 0; r < R_; ++r) {
          const float xi = xb[r * NN + i];
          const float4 xj =
              *reinterpret_cast<const float4*>(xb + r * NN + 4 * q);
          a.x = fmaf(xi, xj.x, a.x);
          a.y = fmaf(xi, xj.y, a.y);
          a.z = fmaf(xi, xj.z, a.z);
          a.w = fmaf(xi, xj.w, a.w);
        }
        av[u] = a;
      }
    }
    // issue the 4 stores back-to-back -> 4 outstanding per wave
#pragma unroll
    for (int u = 0; u < 4; ++u) {
      const int fg = base + u * 256;
      if (fg < total) ob[fg] = av[u];  // lanes consecutive -> 1KB coalesced
    }
  }
}

extern "C" void kernel_launch(void* const* d_in, const int* in_sizes, int n_in,
                              void* d_out, int out_size, void* d_ws, size_t ws_size,
                              hipStream_t stream) {
  const float* z    = (const float*)d_in[0];  // (16384, 68)
  const int*   adj  = (const int*)  d_in[1];  // (68, 32)
  const float* fc_w = (const float*)d_in[2];  // (5, 68, 68)
  const float* fc_b = (const float*)d_in[3];  // (5, 68)
  const float* gw   = (const float*)d_in[4];  // (5, 3, 68, 32)
  const float* gb   = (const float*)d_in[5];  // (5, 3, 68)
  float* out = (float*)d_out;                 // (16384, 4624)

  const int B = in_sizes[0] / LAT;            // 16384
  // ws layout (f32): wpad[108800] | bpad[1600] | zT[68*B] | X[340*B] ~27.2MB
  float* wpad = (float*)d_ws;
  float* bpad = wpad + WPAD_FLOATS;
  float* zT = bpad + BPAD_FLOATS;
  float* X  = zT + (size_t)LAT * B;

  const int nb = B / 64;                      // 256 batch-groups (chain)

  prep_k<<<NPREP + R_ + B / 64, 256, 0, stream>>>(z, adj, fc_w, fc_b, gw, gb,
                                                  wpad, bpad, zT, B);
  chain_k<<<R_ * nb, 256, 0, stream>>>(zT, wpad, bpad, X, B, nb);
  outer_k<<<B / BBK2, 256, 0, stream>>>(X, out, B);
}

// Round 21
// 124.911 us; speedup vs baseline: 2.2641x; 2.2641x over previous
//
#include <hip/hip_runtime.h>
#include <math.h>

// Problem constants
#define R_ 5
#define NN 68        // N_NODES == LATENT
#define KK 32        // neighbors per node
#define NL 3         // GCN layers
#define LAT 68
#define NSL 17               // nodes per wave slice (4 waves x 17 = 68)
#define ROWQ (NN / 4)        // 17 float4 per node row
#define NF4 ((NN * NN) / 4)  // 1156 float4 per output row
#define BBK2 16              // batches per K2 block
#define LSTR 344             // LDS row stride (floats) for K2, 16B-aligned
#define NPREP (R_ * NL)      // 15 densify blocks inside prep_k

// ---------------- P: merged prep (densify + z-transpose) ----------------
__global__ __launch_bounds__(256) void prep_k(
    const float* __restrict__ z, const int* __restrict__ adj,
    const float* __restrict__ gw, float* __restrict__ wd,
    float* __restrict__ zT, int B) {
  const int t = threadIdx.x;
  if (blockIdx.x < NPREP) {
    const int rl = blockIdx.x;  // r*NL + l
    __shared__ float col[NN][NN + 4];
    for (int i = t; i < NN * (NN + 4); i += 256) (&col[0][0])[i] = 0.0f;
    __syncthreads();
    if (t < NN) {
      const int n = t;  // thread owns column n -> no races
      const int* ar = adj + n * KK;
      const float* wr = gw + ((size_t)rl * NN + n) * KK;
      for (int k = 0; k < KK; ++k) col[ar[k]][n] += wr[k];
    }
    __syncthreads();
    float* wout = wd + (size_t)rl * NN * NN;  // [m][n], n contiguous
    for (int i = t; i < NN * NN; i += 256) {
      const int m = i / NN, n = i - m * NN;
      wout[i] = col[m][n];
    }
  } else {
    const int b0 = (blockIdx.x - NPREP) * 64;
    __shared__ float zls[64][LAT + 1];  // +1: stride 69, conflict-free
    for (int idx = t; idx < 64 * ROWQ; idx += 256) {
      const int row = idx / ROWQ, q = idx - row * ROWQ;
      const float4 v =
          *reinterpret_cast<const float4*>(z + (size_t)(b0 + row) * LAT + 4 * q);
      zls[row][4 * q + 0] = v.x;
      zls[row][4 * q + 1] = v.y;
      zls[row][4 * q + 2] = v.z;
      zls[row][4 * q + 3] = v.w;
    }
    __syncthreads();
    for (int idx = t; idx < LAT * 64; idx += 256) {
      const int l = idx >> 6, bb = idx & 63;
      zT[(size_t)l * B + b0 + bb] = zls[bb][l];
    }
  }
}

// ---------------- K1: GEMM-chain (v12 — chunked m, scalar s_load path) -----
// Wave w owns node slice [17w,17w+17), base wave-uniform via readfirstlane ->
// weight/bias addresses scalarize to s_load (constant-cache broadcast: the
// measured-best weight path; VMEM per-lane loads are 5x worse — R20).
// m-loop chunked by 17: chunk's xm values hoisted into statically-indexed
// VGPRs so the 289-fmac body waits only on the SMEM stream (DS+SMEM share
// lgkmcnt; SMEM completes out-of-order -> per-m interleave forced a full
// drain every 34 VALU cycles; chunking cuts drains 68 -> ~4 per stage,
// -13us measured at R12). Do NOT fully unroll mb or prefetch xmv (R17/R19).
__global__ __launch_bounds__(256) void chain_k(
    const float* __restrict__ zT, const float* __restrict__ fc_w,
    const float* __restrict__ fc_b, const float* __restrict__ wd,
    const float* __restrict__ gb, float* __restrict__ X, int B, int nb) {
  const int t = threadIdx.x;
  const int lane = t & 63;
  const int w = __builtin_amdgcn_readfirstlane(t >> 6);
  const int n0 = w * NSL;  // first node of this wave's slice (wave-uniform)
  const int r = blockIdx.x / nb;
  const int b0 = (blockIdx.x - r * nb) * 64;

  __shared__ float xs[NN][64];  // 17.4 KB; z, then x, per stage

  for (int idx = t; idx < NN * 64; idx += 256) {
    const int m = idx >> 6;
    xs[m][idx & 63] = zT[(size_t)m * B + b0 + (idx & 63)];
  }
  __syncthreads();

  float acc[NSL];

#pragma unroll 1
  for (int stage = 0; stage < 1 + NL; ++stage) {
    const float* wb = (stage == 0) ? fc_w + (size_t)r * LAT * NN
                                   : wd + (size_t)(r * NL + stage - 1) * NN * NN;
    const float* bias = (stage == 0) ? fc_b + r * NN
                                     : gb + (size_t)(r * NL + stage - 1) * NN;
#pragma unroll
    for (int j = 0; j < NSL; ++j) acc[j] = bias[n0 + j];  // uniform -> s_load

#pragma unroll 1
    for (int mb = 0; mb < 4; ++mb) {  // 4 chunks of 17 rows
      float xmv[NSL];                 // statically indexed -> stays in VGPRs
#pragma unroll
      for (int k = 0; k < NSL; ++k) xmv[k] = xs[mb * NSL + k][lane];
      const float* wrb = wb + (size_t)(mb * NSL) * NN + n0;
#pragma unroll
      for (int k = 0; k < NSL; ++k) {
        const float* wr = wrb + (size_t)k * NN;  // wave-uniform -> s_load
#pragma unroll
        for (int j = 0; j < NSL; ++j) acc[j] = fmaf(xmv[k], wr[j], acc[j]);
      }
    }
    if (stage > 0) {
#pragma unroll
      for (int j = 0; j < NSL; ++j)
        acc[j] = 1.0f / (1.0f + __expf(-acc[j]));
    }
    if (stage < NL) {
      __syncthreads();  // everyone done READING xs for this stage
#pragma unroll
      for (int j = 0; j < NSL; ++j) xs[n0 + j][lane] = acc[j];
      __syncthreads();
    }
  }

  // ---- final X -> ws, layout [r*68+n][b]: coalesced 256B rows ----
  float* Xb = X + ((size_t)r * NN + n0) * B + b0 + lane;
#pragma unroll
  for (int j = 0; j < NSL; ++j) Xb[(size_t)j * B] = acc[j];
}

// ---------------- K2: outer product, flat store, 4-DEEP STORE PIPELINE -----
// Flat coalesced stores (consecutive lanes = consecutive f4, 1KB/instr,
// full-line coverage) + 4 independent accumulator sets per macro-iteration
// with stores issued back-to-back: 4 KB in flight per wave instead of 1 KB
// (single-outstanding-store was the shared property of all 73-80us variants;
// 4-deep measured -2.6us; 8-deep neutral/worse — R19).
__global__ __launch_bounds__(256) void outer_k(const float* __restrict__ X,
                                               float* __restrict__ out, int B) {
  const int t = threadIdx.x;
  const int b0 = blockIdx.x * BBK2;
  __shared__ float xls[BBK2 * LSTR];

  // stage X[rn][b0..b0+15] -> xls[bb][rn]; reads are exact 64B lines
  for (int idx = t; idx < R_ * NN * BBK2; idx += 256) {
    const int rn = idx >> 4, bb = idx & (BBK2 - 1);
    xls[bb * LSTR + rn] = X[(size_t)rn * B + b0 + bb];
  }
  __syncthreads();

  float4* ob = reinterpret_cast<float4*>(out) + (size_t)b0 * NF4;
  const int total = BBK2 * NF4;  // 18496 = 18*1024 + 64
#pragma unroll 1
  for (int base = t; base < total; base += 1024) {
    float4 av[4];  // 4 independent accumulator sets (statically indexed)
#pragma unroll
    for (int u = 0; u < 4; ++u) {
      const int fg = base + u * 256;
      if (fg < total) {
        const int bb = fg / NF4;
        const int f = fg - bb * NF4;
        const int i = f / ROWQ;
        const int q = f - i * ROWQ;
        const float* xb = &xls[bb * LSTR];
        float4 a = make_float4(0.f, 0.f, 0.f, 0.f);
#pragma unroll
        for (int r = 0; r < R_; ++r) {
          const float xi = xb[r * NN + i];
          const float4 xj =
              *reinterpret_cast<const float4*>(xb + r * NN + 4 * q);
          a.x = fmaf(xi, xj.x, a.x);
          a.y = fmaf(xi, xj.y, a.y);
          a.z = fmaf(xi, xj.z, a.z);
          a.w = fmaf(xi, xj.w, a.w);
        }
        av[u] = a;
      }
    }
    // issue the 4 stores back-to-back -> 4 outstanding per wave
#pragma unroll
    for (int u = 0; u < 4; ++u) {
      const int fg = base + u * 256;
      if (fg < total) ob[fg] = av[u];  // lanes consecutive -> 1KB coalesced
    }
  }
}

extern "C" void kernel_launch(void* const* d_in, const int* in_sizes, int n_in,
                              void* d_out, int out_size, void* d_ws, size_t ws_size,
                              hipStream_t stream) {
  const float* z    = (const float*)d_in[0];  // (16384, 68)
  const int*   adj  = (const int*)  d_in[1];  // (68, 32)
  const float* fc_w = (const float*)d_in[2];  // (5, 68, 68)
  const float* fc_b = (const float*)d_in[3];  // (5, 68)
  const float* gw   = (const float*)d_in[4];  // (5, 3, 68, 32)
  const float* gb   = (const float*)d_in[5];  // (5, 3, 68)
  float* out = (float*)d_out;                 // (16384, 4624)

  const int B = in_sizes[0] / LAT;            // 16384
  // ws layout (f32): wd[15*68*68] | zT[68*B] | X[340*B]  (~27.1 MB total)
  float* wd = (float*)d_ws;
  float* zT = wd + R_ * NL * NN * NN;
  float* X  = zT + (size_t)LAT * B;

  const int nb = B / 64;                      // 256 batch-groups (chain)

  prep_k<<<NPREP + B / 64, 256, 0, stream>>>(z, adj, gw, wd, zT, B);
  chain_k<<<R_ * nb, 256, 0, stream>>>(zT, fc_w, fc_b, wd, gb, X, B, nb);
  outer_k<<<B / BBK2, 256, 0, stream>>>(X, out, B);
}

// Round 22
// 124.400 us; speedup vs baseline: 2.2734x; 1.0041x over previous
//
#include <hip/hip_runtime.h>
#include <math.h>

// Problem constants
#define R_ 5
#define NN 68        // N_NODES == LATENT
#define KK 32        // neighbors per node
#define NL 3         // GCN layers
#define LAT 68
#define NSL 17               // nodes per wave slice (4 waves x 17 = 68)
#define ROWQ (NN / 4)        // 17 float4 per node row
#define NF4 ((NN * NN) / 4)  // 1156 float4 per output row
#define BBK2 16              // batches per K2 block
#define LSTR 344             // LDS row stride (floats) for K2, 16B-aligned
#define XSP 65               // chain xs stride: transpose-write ~2-way, read free

// ---------------- P: densify only (15 blocks; zT eliminated) ----------------
__global__ __launch_bounds__(256) void prep_k(
    const int* __restrict__ adj, const float* __restrict__ gw,
    float* __restrict__ wd) {
  const int t = threadIdx.x;
  const int rl = blockIdx.x;  // r*NL + l
  __shared__ float col[NN][NN + 4];
  for (int i = t; i < NN * (NN + 4); i += 256) (&col[0][0])[i] = 0.0f;
  __syncthreads();
  if (t < NN) {
    const int n = t;  // thread owns column n -> no races
    const int* ar = adj + n * KK;
    const float* wr = gw + ((size_t)rl * NN + n) * KK;
    for (int k = 0; k < KK; ++k) col[ar[k]][n] += wr[k];
  }
  __syncthreads();
  float* wout = wd + (size_t)rl * NN * NN;  // [m][n], n contiguous
  for (int i = t; i < NN * NN; i += 256) {
    const int m = i / NN, n = i - m * NN;
    wout[i] = col[m][n];
  }
}

// ---------------- K1: GEMM-chain (v12 compute; in-block z transpose) -------
// Staging change only: each block reads its own 64x68 z tile as coalesced
// float4 and writes transposed into xs (stride 65 -> ~2-way conflicts, free;
// compute read (lane+m)%32 -> free). Kills the zT HBM round-trip and prep's
// 256 transpose blocks. Compute loop is v12 verbatim: scalar s_load weights,
// m chunked by 17 (R12's -13us: lgkmcnt drains 68 -> ~4 per stage).
__global__ __launch_bounds__(256) void chain_k(
    const float* __restrict__ z, const float* __restrict__ fc_w,
    const float* __restrict__ fc_b, const float* __restrict__ wd,
    const float* __restrict__ gb, float* __restrict__ X, int B, int nb) {
  const int t = threadIdx.x;
  const int lane = t & 63;
  const int w = __builtin_amdgcn_readfirstlane(t >> 6);
  const int n0 = w * NSL;  // first node of this wave's slice (wave-uniform)
  const int r = blockIdx.x / nb;
  const int b0 = (blockIdx.x - r * nb) * 64;

  __shared__ float xs[NN][XSP];  // 17.7 KB; z (transposed), then x, per stage

  // stage z tile transposed: read z[b0+row][4q..4q+3] (coalesced f4),
  // write xs[4q+i][row] (stride-65 -> ~2-way bank aliasing, free)
  for (int idx = t; idx < 64 * ROWQ; idx += 256) {
    const int row = idx / ROWQ, q = idx - row * ROWQ;
    const float4 v =
        *reinterpret_cast<const float4*>(z + (size_t)(b0 + row) * LAT + 4 * q);
    xs[4 * q + 0][row] = v.x;
    xs[4 * q + 1][row] = v.y;
    xs[4 * q + 2][row] = v.z;
    xs[4 * q + 3][row] = v.w;
  }
  __syncthreads();

  float acc[NSL];

#pragma unroll 1
  for (int stage = 0; stage < 1 + NL; ++stage) {
    const float* wb = (stage == 0) ? fc_w + (size_t)r * LAT * NN
                                   : wd + (size_t)(r * NL + stage - 1) * NN * NN;
    const float* bias = (stage == 0) ? fc_b + r * NN
                                     : gb + (size_t)(r * NL + stage - 1) * NN;
#pragma unroll
    for (int j = 0; j < NSL; ++j) acc[j] = bias[n0 + j];  // uniform -> s_load

#pragma unroll 1
    for (int mb = 0; mb < 4; ++mb) {  // 4 chunks of 17 rows
      float xmv[NSL];                 // statically indexed -> stays in VGPRs
#pragma unroll
      for (int k = 0; k < NSL; ++k) xmv[k] = xs[mb * NSL + k][lane];
      const float* wrb = wb + (size_t)(mb * NSL) * NN + n0;
#pragma unroll
      for (int k = 0; k < NSL; ++k) {
        const float* wr = wrb + (size_t)k * NN;  // wave-uniform -> s_load
#pragma unroll
        for (int j = 0; j < NSL; ++j) acc[j] = fmaf(xmv[k], wr[j], acc[j]);
      }
    }
    if (stage > 0) {
#pragma unroll
      for (int j = 0; j < NSL; ++j)
        acc[j] = 1.0f / (1.0f + __expf(-acc[j]));
    }
    if (stage < NL) {
      __syncthreads();  // everyone done READING xs for this stage
#pragma unroll
      for (int j = 0; j < NSL; ++j) xs[n0 + j][lane] = acc[j];
      __syncthreads();
    }
  }

  // ---- final X -> ws, layout [r*68+n][b]: coalesced 256B rows ----
  float* Xb = X + ((size_t)r * NN + n0) * B + b0 + lane;
#pragma unroll
  for (int j = 0; j < NSL; ++j) Xb[(size_t)j * B] = acc[j];
}

// ---------------- K2: outer product, flat store, 4-DEEP STORE PIPELINE -----
// (R16 verbatim — measured best; 8-deep neutral/worse, nt worse, obuf worse)
__global__ __launch_bounds__(256) void outer_k(const float* __restrict__ X,
                                               float* __restrict__ out, int B) {
  const int t = threadIdx.x;
  const int b0 = blockIdx.x * BBK2;
  __shared__ float xls[BBK2 * LSTR];

  // stage X[rn][b0..b0+15] -> xls[bb][rn]; reads are exact 64B lines
  for (int idx = t; idx < R_ * NN * BBK2; idx += 256) {
    const int rn = idx >> 4, bb = idx & (BBK2 - 1);
    xls[bb * LSTR + rn] = X[(size_t)rn * B + b0 + bb];
  }
  __syncthreads();

  float4* ob = reinterpret_cast<float4*>(out) + (size_t)b0 * NF4;
  const int total = BBK2 * NF4;  // 18496 = 18*1024 + 64
#pragma unroll 1
  for (int base = t; base < total; base += 1024) {
    float4 av[4];  // 4 independent accumulator sets (statically indexed)
#pragma unroll
    for (int u = 0; u < 4; ++u) {
      const int fg = base + u * 256;
      if (fg < total) {
        const int bb = fg / NF4;
        const int f = fg - bb * NF4;
        const int i = f / ROWQ;
        const int q = f - i * ROWQ;
        const float* xb = &xls[bb * LSTR];
        float4 a = make_float4(0.f, 0.f, 0.f, 0.f);
#pragma unroll
        for (int r = 0; r < R_; ++r) {
          const float xi = xb[r * NN + i];
          const float4 xj =
              *reinterpret_cast<const float4*>(xb + r * NN + 4 * q);
          a.x = fmaf(xi, xj.x, a.x);
          a.y = fmaf(xi, xj.y, a.y);
          a.z = fmaf(xi, xj.z, a.z);
          a.w = fmaf(xi, xj.w, a.w);
        }
        av[u] = a;
      }
    }
    // issue the 4 stores back-to-back -> 4 outstanding per wave
#pragma unroll
    for (int u = 0; u < 4; ++u) {
      const int fg = base + u * 256;
      if (fg < total) ob[fg] = av[u];  // lanes consecutive -> 1KB coalesced
    }
  }
}

extern "C" void kernel_launch(void* const* d_in, const int* in_sizes, int n_in,
                              void* d_out, int out_size, void* d_ws, size_t ws_size,
                              hipStream_t stream) {
  const float* z    = (const float*)d_in[0];  // (16384, 68)
  const int*   adj  = (const int*)  d_in[1];  // (68, 32)
  const float* fc_w = (const float*)d_in[2];  // (5, 68, 68)
  const float* fc_b = (const float*)d_in[3];  // (5, 68)
  const float* gw   = (const float*)d_in[4];  // (5, 3, 68, 32)
  const float* gb   = (const float*)d_in[5];  // (5, 3, 68)
  float* out = (float*)d_out;                 // (16384, 4624)

  const int B = in_sizes[0] / LAT;            // 16384
  // ws layout (f32): wd[15*68*68] | X[340*B]  (~22.6 MB total)
  float* wd = (float*)d_ws;
  float* X  = wd + R_ * NL * NN * NN;

  const int nb = B / 64;                      // 256 batch-groups (chain)

  prep_k<<<R_ * NL, 256, 0, stream>>>(adj, gw, wd);
  chain_k<<<R_ * nb, 256, 0, stream>>>(z, fc_w, fc_b, wd, gb, X, B, nb);
  outer_k<<<B / BBK2, 256, 0, stream>>>(X, out, B);
}